// Round 2
// baseline (167.847 us; speedup 1.0000x reference)
//
#include <hip/hip_runtime.h>
#include <math.h>

// MFMA-based fused autoencoder fwd + Jacobians, 16x16x16 restructure.
// Per wave: 64 samples = 4 slices of 16 columns. Per layer:
//   D[i,s] = sum_j W[i,j] * H[j,s]  via  v_mfma_f32_16x16x16_bf16 (K=16 exact)
// Layouts (CDNA standard, m89-verified family):
//   A: row=l&15, k=(l>>4)*4+j    B: k=(l>>4)*4+j, col=l&15
//   D: row=(l>>4)*4+reg, col=l&15
// KEY: D rows per lane == next-B k-range per lane -> layer2->3 is lane-local
// (no shfl/bpermute/permlane anywhere). W3 duplicated at rows {0,1,4,5,8,9,
// 12,13} -> every lane's acc regs 0,1 = theta of its column -> enc->dec also
// lane-local. Shared read-only C operands (bias tuple / zero tuple) replace
// per-call acc zero-init movs. Lane l stores sample base+l (full-wave
// coalesced stores); slice results selected by c==g with 3 cndmask/value.

typedef float  f32x4  __attribute__((ext_vector_type(4)));
typedef short  bf16x4 __attribute__((ext_vector_type(4)));

__device__ __forceinline__ unsigned short f2bf1(float f) {   // RNE (prep only)
    unsigned u = __builtin_bit_cast(unsigned, f);
    u += 0x7FFFu + ((u >> 16) & 1u);
    return (unsigned short)(u >> 16);
}

// packed truncating f32->bf16 pair: 1 x v_perm_b32 (a -> low half)
__device__ __forceinline__ unsigned packbf(float a, float b) {
    return __builtin_amdgcn_perm(__builtin_bit_cast(unsigned, b),
                                 __builtin_bit_cast(unsigned, a), 0x07060302u);
}

__device__ __forceinline__ bf16x4 pack4(float a, float b, float c, float d) {
    union { unsigned u[2]; bf16x4 f; } x;
    x.u[0] = packbf(a, b); x.u[1] = packbf(c, d);
    return x.f;
}

__device__ __forceinline__ f32x4 mfma16(bf16x4 a, bf16x4 b, f32x4 c) {
#if __has_builtin(__builtin_amdgcn_mfma_f32_16x16x16bf16_1k)
    return __builtin_amdgcn_mfma_f32_16x16x16bf16_1k(a, b, c, 0, 0, 0);
#else
    f32x4 d;
    asm("v_mfma_f32_16x16x16_bf16 %0, %1, %2, %3"
        : "=&v"(d) : "v"(a), "v"(b), "v"(c));
    return d;
#endif
}

// softplus + sigmoid in 6 VALU (3 trans):
//   t = exp(-z); sg = rcp(1+t); sp = z - ln(sg)
__device__ __forceinline__ void activ(float z, float& sp, float& sg) {
    float t = __expf(-z);
    sg = __builtin_amdgcn_rcpf(1.0f + t);
    sp = fmaf(-0.69314718056f, __log2f(sg), z);
}

// ---- ws layout (float offsets) ----
// encL1 [64][12] @0     (wa[4] | wb[4] | bias[4], rows g*4..g*4+3)
// decL1 @768
// encB2 [64][4] @1536   (zc C-init: b2[g*4+r])
// decB2 @1792
// frags (shorts) @2048 floats: A2e[64][4] | A3e | A2d | A3d
__global__ void prep_kernel(
    const float* __restrict__ ew1, const float* __restrict__ eb1,
    const float* __restrict__ ew2, const float* __restrict__ eb2,
    const float* __restrict__ ew3,
    const float* __restrict__ dw1, const float* __restrict__ db1,
    const float* __restrict__ dw2, const float* __restrict__ db2,
    const float* __restrict__ dw3,
    float* __restrict__ ws)
{
    const int t = threadIdx.x;
    if (t >= 64) return;
    const int g = t >> 4, m = t & 15;
    unsigned short* frag = (unsigned short*)(ws + 2048);
#pragma unroll
    for (int j = 0; j < 4; ++j) {
        const int i = g * 4 + j;             // L1 neuron row == A-frag k index
        ws[t*12 + j]           = ew1[2*i];
        ws[t*12 + 4 + j]       = ew1[2*i + 1];
        ws[t*12 + 8 + j]       = eb1[i];
        ws[768 + t*12 + j]     = dw1[2*i];
        ws[768 + t*12 + 4 + j] = dw1[2*i + 1];
        ws[768 + t*12 + 8 + j] = db1[i];
        ws[1536 + t*4 + j]     = eb2[i];
        ws[1792 + t*4 + j]     = db2[i];
        frag[t*4 + j]       = f2bf1(ew2[m*16 + i]);   // A2: row m, k=i
        frag[512 + t*4 + j] = f2bf1(dw2[m*16 + i]);
        // A3: W3 duplicated at rows where (row&3)<2 -> every lane's D regs
        // 0,1 carry theta0/theta1 of its column.
        const int r3 = m & 3;
        frag[256 + t*4 + j] = (r3 < 2) ? f2bf1(ew3[r3*16 + i]) : (unsigned short)0;
        frag[768 + t*4 + j] = (r3 < 2) ? f2bf1(dw3[r3*16 + i]) : (unsigned short)0;
    }
}

__device__ __forceinline__ void mlp16(
    f32x4 Wa, f32x4 Wb, f32x4 Bb, f32x4 B2c,
    bf16x4 A2, bf16x4 A3, f32x4 C3, f32x4 Z,
    float x, float y,
    float& o0, float& o1, float& J00, float& J01, float& J10, float& J11)
{
    float h[4], ta[4], tb[4];
#pragma unroll
    for (int j = 0; j < 4; ++j) {
        float z = fmaf(Wa[j], x, fmaf(Wb[j], y, Bb[j]));
        float sp, sg; activ(z, sp, sg);
        h[j] = sp; ta[j] = sg * Wa[j]; tb[j] = sg * Wb[j];
    }
    // C operands are shared read-only tuples: bias tuple for values, Z for
    // Jacobian accs -> no per-call acc init.
    f32x4 zc = mfma16(A2, pack4(h[0],  h[1],  h[2],  h[3]),  B2c);
    f32x4 ua = mfma16(A2, pack4(ta[0], ta[1], ta[2], ta[3]), Z);
    f32x4 ub = mfma16(A2, pack4(tb[0], tb[1], tb[2], tb[3]), Z);

    float h2[4], sa[4], sb[4];
#pragma unroll
    for (int r = 0; r < 4; ++r) {
        float sp, sg; activ(zc[r], sp, sg);
        h2[r] = sp; sa[r] = sg * ua[r]; sb[r] = sg * ub[r];
    }
    // D rows (g*4+r) == B k-range (g*4+j): feed straight back, no exchange.
    f32x4 oz = mfma16(A3, pack4(h2[0], h2[1], h2[2], h2[3]), C3);
    f32x4 oa = mfma16(A3, pack4(sa[0], sa[1], sa[2], sa[3]), Z);
    f32x4 ob = mfma16(A3, pack4(sb[0], sb[1], sb[2], sb[3]), Z);
    o0 = oz[0]; o1 = oz[1];
    J00 = oa[0]; J10 = oa[1]; J01 = ob[0]; J11 = ob[1];
}

__device__ __forceinline__ float sel4(const float* v, int g) {
    float a = (g & 1) ? v[1] : v[0];
    float b = (g & 1) ? v[3] : v[2];
    return (g & 2) ? b : a;
}

__global__ __launch_bounds__(256) void ae_mfma_kernel(
    const float* __restrict__ q,
    const float* __restrict__ eb3, const float* __restrict__ db3,
    const float* __restrict__ ws, float* __restrict__ out, int n)
{
    const int lane = threadIdx.x & 63;
    const int wv = blockIdx.x * 4 + (threadIdx.x >> 6);
    const int g = lane >> 4, m16 = lane & 15;
    const long base = (long)wv * 64;           // 64 samples per wave
    if (base >= n) return;                     // wave-uniform exit

    const f32x4 eWa = *(const f32x4*)(ws + (size_t)lane*12);
    const f32x4 eWb = *(const f32x4*)(ws + (size_t)lane*12 + 4);
    const f32x4 eBb = *(const f32x4*)(ws + (size_t)lane*12 + 8);
    const f32x4 dWa = *(const f32x4*)(ws + 768 + (size_t)lane*12);
    const f32x4 dWb = *(const f32x4*)(ws + 768 + (size_t)lane*12 + 4);
    const f32x4 dBb = *(const f32x4*)(ws + 768 + (size_t)lane*12 + 8);
    const f32x4 eB2 = *(const f32x4*)(ws + 1536 + (size_t)lane*4);
    const f32x4 dB2 = *(const f32x4*)(ws + 1792 + (size_t)lane*4);
    const bf16x4* fr = (const bf16x4*)(ws + 2048);
    const bf16x4 A2e = fr[lane],       A3e = fr[64 + lane];
    const bf16x4 A2d = fr[128 + lane], A3d = fr[192 + lane];
    f32x4 C3e; C3e[0] = eb3[0]; C3e[1] = eb3[1]; C3e[2] = 0.0f; C3e[3] = 0.0f;
    f32x4 C3d; C3d[0] = db3[0]; C3d[1] = db3[1]; C3d[2] = 0.0f; C3d[3] = 0.0f;
    f32x4 Z;   Z[0] = 0.0f; Z[1] = 0.0f; Z[2] = 0.0f; Z[3] = 0.0f;

    // slice c columns = samples base + c*16 + m16
    float xs[4], ys[4];
#pragma unroll
    for (int c = 0; c < 4; ++c) {
        long s = base + c*16 + m16;
        long si = s < n ? s : (long)n - 1;
        const float2 qv = ((const float2*)q)[si];
        xs[c] = qv.x; ys[c] = qv.y;
    }

    float eo0[4], eo1[4], E00[4], E01[4], E10[4], E11[4];
    float qo0[4], qo1[4], D00[4], D01[4], D10[4], D11[4];
#pragma unroll
    for (int c = 0; c < 4; ++c) {
        mlp16(eWa, eWb, eBb, eB2, A2e, A3e, C3e, Z, xs[c], ys[c],
              eo0[c], eo1[c], E00[c], E01[c], E10[c], E11[c]);
        // theta lane-local (W3 row-duplication) -> feed dec directly
        mlp16(dWa, dWb, dBb, dB2, A2d, A3d, C3d, Z, eo0[c], eo1[c],
              qo0[c], qo1[c], D00[c], D01[c], D10[c], D11[c]);
    }

    // lane l stores sample base+l  (its column in slice c == g)
    const long sp = base + lane;
    if (sp < n) {
        const float x = sel4(xs, g), y = sel4(ys, g);
        const float r2   = fmaf(x, x, y * y);
        const float iv   = __builtin_amdgcn_rcpf(r2);
        const float rinv = __builtin_amdgcn_rsqf(r2 + 1e-8f);
        const size_t nn = (size_t)n;
        ((float2*)(out))[sp]           = make_float2(sel4(eo0,g), sel4(eo1,g));
        ((float4*)(out + 2 * nn))[sp]  = make_float4(sel4(E00,g), sel4(E01,g),
                                                     sel4(E10,g), sel4(E11,g));
        ((float2*)(out + 6 * nn))[sp]  = make_float2(sel4(qo0,g), sel4(qo1,g));
        ((float4*)(out + 8 * nn))[sp]  = make_float4(sel4(D00,g), sel4(D01,g),
                                                     sel4(D10,g), sel4(D11,g));
        ((float4*)(out + 12 * nn))[sp] = make_float4(-y * iv, x * iv,
                                                     x * rinv, y * rinv);
    }
}

extern "C" void kernel_launch(void* const* d_in, const int* in_sizes, int n_in,
                              void* d_out, int out_size, void* d_ws, size_t ws_size,
                              hipStream_t stream)
{
    const float* q   = (const float*)d_in[0];
    const float* ew1 = (const float*)d_in[1];
    const float* eb1 = (const float*)d_in[2];
    const float* ew2 = (const float*)d_in[3];
    const float* eb2 = (const float*)d_in[4];
    const float* ew3 = (const float*)d_in[5];
    const float* eb3 = (const float*)d_in[6];
    const float* dw1 = (const float*)d_in[7];
    const float* db1 = (const float*)d_in[8];
    const float* dw2 = (const float*)d_in[9];
    const float* db2 = (const float*)d_in[10];
    const float* dw3 = (const float*)d_in[11];
    const float* db3 = (const float*)d_in[12];

    const int n = in_sizes[0] / 2;
    float* ws = (float*)d_ws;

    prep_kernel<<<1, 64, 0, stream>>>(ew1, eb1, ew2, eb2, ew3,
                                      dw1, db1, dw2, db2, dw3, ws);

    const int waves  = (n + 63) / 64;
    const int blocks = (waves + 3) / 4;
    ae_mfma_kernel<<<blocks, 256, 0, stream>>>(q, eb3, db3, ws, (float*)d_out, n);
}

// Round 3
// 127.334 us; speedup vs baseline: 1.3182x; 1.3182x over previous
//
#include <hip/hip_runtime.h>
#include <math.h>

// MFMA-based fused autoencoder fwd + Jacobians, 16x16x16, slice-unrolled.
// Per wave: 64 samples = 4 slices of 16 columns. Per layer:
//   D[i,s] = sum_j W[i,j] * H[j,s]  via  v_mfma_f32_16x16x16_bf16 (K=16 exact)
// Layouts: A: row=l&15, k=(l>>4)*4+j   B: k=(l>>4)*4+j, col=l&15
//          D: row=(l>>4)*4+reg, col=l&15
// D rows per lane == next-B k-range per lane -> layer2->3 lane-local; W3
// duplicated at rows {r: r&3<2} -> every lane's D regs 0,1 = theta of its
// column -> enc->dec lane-local. No cross-lane ops anywhere.
//
// R3 fix vs R2 (which regressed 56->82us): R2's slice loop held runtime-
// indexed private arrays (xs[c], eo0[c]...) -> AMDGPUPromoteAlloca moved
// 80 B/thread to LDS (LDS_Block_Size=20480, 437k bank conflicts) + scratch
// (WRITE_SIZE 3.2x). R3: slices manually unrolled with named scalars, each
// slice stored immediately by its g==c quarter-wave (16 consecutive lanes,
// contiguous segments) so results die per-slice. No private arrays survive.

typedef float  f32x4  __attribute__((ext_vector_type(4)));
typedef short  bf16x4 __attribute__((ext_vector_type(4)));

__device__ __forceinline__ unsigned short f2bf1(float f) {   // RNE (prep only)
    unsigned u = __builtin_bit_cast(unsigned, f);
    u += 0x7FFFu + ((u >> 16) & 1u);
    return (unsigned short)(u >> 16);
}

// packed truncating f32->bf16 pair: 1 x v_perm_b32 (a -> low half)
__device__ __forceinline__ unsigned packbf(float a, float b) {
    return __builtin_amdgcn_perm(__builtin_bit_cast(unsigned, b),
                                 __builtin_bit_cast(unsigned, a), 0x07060302u);
}

__device__ __forceinline__ bf16x4 pack4(float a, float b, float c, float d) {
    union { unsigned u[2]; bf16x4 f; } x;
    x.u[0] = packbf(a, b); x.u[1] = packbf(c, d);
    return x.f;
}

__device__ __forceinline__ f32x4 mfma16(bf16x4 a, bf16x4 b, f32x4 c) {
#if __has_builtin(__builtin_amdgcn_mfma_f32_16x16x16bf16_1k)
    return __builtin_amdgcn_mfma_f32_16x16x16bf16_1k(a, b, c, 0, 0, 0);
#else
    f32x4 d;
    asm("v_mfma_f32_16x16x16_bf16 %0, %1, %2, %3"
        : "=&v"(d) : "v"(a), "v"(b), "v"(c));
    return d;
#endif
}

// softplus + sigmoid in 6 VALU (3 trans):
//   t = exp(-z); sg = rcp(1+t); sp = z - ln(sg)
__device__ __forceinline__ void activ(float z, float& sp, float& sg) {
    float t = __expf(-z);
    sg = __builtin_amdgcn_rcpf(1.0f + t);
    sp = fmaf(-0.69314718056f, __log2f(sg), z);
}

// ---- ws layout (float offsets) ----
// encL1 [64][12] @0     (wa[4] | wb[4] | bias[4], rows g*4..g*4+3)
// decL1 @768
// encB2 [64][4] @1536   (zc C-init: b2[g*4+r])
// decB2 @1792
// frags (shorts) @2048 floats: A2e[64][4] | A3e | A2d | A3d
__global__ void prep_kernel(
    const float* __restrict__ ew1, const float* __restrict__ eb1,
    const float* __restrict__ ew2, const float* __restrict__ eb2,
    const float* __restrict__ ew3,
    const float* __restrict__ dw1, const float* __restrict__ db1,
    const float* __restrict__ dw2, const float* __restrict__ db2,
    const float* __restrict__ dw3,
    float* __restrict__ ws)
{
    const int t = threadIdx.x;
    if (t >= 64) return;
    const int g = t >> 4, m = t & 15;
    unsigned short* frag = (unsigned short*)(ws + 2048);
#pragma unroll
    for (int j = 0; j < 4; ++j) {
        const int i = g * 4 + j;             // L1 neuron row == A-frag k index
        ws[t*12 + j]           = ew1[2*i];
        ws[t*12 + 4 + j]       = ew1[2*i + 1];
        ws[t*12 + 8 + j]       = eb1[i];
        ws[768 + t*12 + j]     = dw1[2*i];
        ws[768 + t*12 + 4 + j] = dw1[2*i + 1];
        ws[768 + t*12 + 8 + j] = db1[i];
        ws[1536 + t*4 + j]     = eb2[i];
        ws[1792 + t*4 + j]     = db2[i];
        frag[t*4 + j]       = f2bf1(ew2[m*16 + i]);   // A2: row m, k=i
        frag[512 + t*4 + j] = f2bf1(dw2[m*16 + i]);
        // A3: W3 duplicated at rows with (row&3)<2 -> every lane's D regs
        // 0,1 carry theta0/theta1 of its column.
        const int r3 = m & 3;
        frag[256 + t*4 + j] = (r3 < 2) ? f2bf1(ew3[r3*16 + i]) : (unsigned short)0;
        frag[768 + t*4 + j] = (r3 < 2) ? f2bf1(dw3[r3*16 + i]) : (unsigned short)0;
    }
}

__device__ __forceinline__ void mlp16(
    f32x4 Wa, f32x4 Wb, f32x4 Bb, f32x4 B2c,
    bf16x4 A2, bf16x4 A3, f32x4 C3, f32x4 Z,
    float x, float y,
    float& o0, float& o1, float& J00, float& J01, float& J10, float& J11)
{
    float h0, h1, h2, h3, ta0, ta1, ta2, ta3, tb0, tb1, tb2, tb3;
    {
        float z, sp, sg;
        z = fmaf(Wa[0], x, fmaf(Wb[0], y, Bb[0])); activ(z, sp, sg);
        h0 = sp; ta0 = sg * Wa[0]; tb0 = sg * Wb[0];
        z = fmaf(Wa[1], x, fmaf(Wb[1], y, Bb[1])); activ(z, sp, sg);
        h1 = sp; ta1 = sg * Wa[1]; tb1 = sg * Wb[1];
        z = fmaf(Wa[2], x, fmaf(Wb[2], y, Bb[2])); activ(z, sp, sg);
        h2 = sp; ta2 = sg * Wa[2]; tb2 = sg * Wb[2];
        z = fmaf(Wa[3], x, fmaf(Wb[3], y, Bb[3])); activ(z, sp, sg);
        h3 = sp; ta3 = sg * Wa[3]; tb3 = sg * Wb[3];
    }
    // shared read-only C tuples: bias tuple for value acc, Z for Jacobian accs
    f32x4 zc = mfma16(A2, pack4(h0,  h1,  h2,  h3),  B2c);
    f32x4 ua = mfma16(A2, pack4(ta0, ta1, ta2, ta3), Z);
    f32x4 ub = mfma16(A2, pack4(tb0, tb1, tb2, tb3), Z);

    float g0, g1, g2, g3, sa0, sa1, sa2, sa3, sb0, sb1, sb2, sb3;
    {
        float sp, sg;
        activ(zc[0], sp, sg); g0 = sp; sa0 = sg * ua[0]; sb0 = sg * ub[0];
        activ(zc[1], sp, sg); g1 = sp; sa1 = sg * ua[1]; sb1 = sg * ub[1];
        activ(zc[2], sp, sg); g2 = sp; sa2 = sg * ua[2]; sb2 = sg * ub[2];
        activ(zc[3], sp, sg); g3 = sp; sa3 = sg * ua[3]; sb3 = sg * ub[3];
    }
    // D rows (g*4+r) == B k-range (g*4+j): feed straight back, lane-local.
    f32x4 oz = mfma16(A3, pack4(g0,  g1,  g2,  g3),  C3);
    f32x4 oa = mfma16(A3, pack4(sa0, sa1, sa2, sa3), Z);
    f32x4 ob = mfma16(A3, pack4(sb0, sb1, sb2, sb3), Z);
    o0 = oz[0]; o1 = oz[1];
    J00 = oa[0]; J10 = oa[1]; J01 = ob[0]; J11 = ob[1];
}

__global__ __launch_bounds__(256) void ae_mfma_kernel(
    const float* __restrict__ q,
    const float* __restrict__ eb3, const float* __restrict__ db3,
    const float* __restrict__ ws, float* __restrict__ out, int n)
{
    const int lane = threadIdx.x & 63;
    const int wv = blockIdx.x * 4 + (threadIdx.x >> 6);
    const int g = lane >> 4, m16 = lane & 15;
    const long base = (long)wv * 64;           // 64 samples per wave
    if (base >= n) return;                     // wave-uniform exit

    const f32x4 eWa = *(const f32x4*)(ws + (size_t)lane*12);
    const f32x4 eWb = *(const f32x4*)(ws + (size_t)lane*12 + 4);
    const f32x4 eBb = *(const f32x4*)(ws + (size_t)lane*12 + 8);
    const f32x4 dWa = *(const f32x4*)(ws + 768 + (size_t)lane*12);
    const f32x4 dWb = *(const f32x4*)(ws + 768 + (size_t)lane*12 + 4);
    const f32x4 dBb = *(const f32x4*)(ws + 768 + (size_t)lane*12 + 8);
    const f32x4 eB2 = *(const f32x4*)(ws + 1536 + (size_t)lane*4);
    const f32x4 dB2 = *(const f32x4*)(ws + 1792 + (size_t)lane*4);
    const bf16x4* fr = (const bf16x4*)(ws + 2048);
    const bf16x4 A2e = fr[lane],       A3e = fr[64 + lane];
    const bf16x4 A2d = fr[128 + lane], A3d = fr[192 + lane];
    f32x4 C3e; C3e[0] = eb3[0]; C3e[1] = eb3[1]; C3e[2] = 0.0f; C3e[3] = 0.0f;
    f32x4 C3d; C3d[0] = db3[0]; C3d[1] = db3[1]; C3d[2] = 0.0f; C3d[3] = 0.0f;
    f32x4 Z;   Z[0] = 0.0f; Z[1] = 0.0f; Z[2] = 0.0f; Z[3] = 0.0f;

    const size_t nn = (size_t)n;

#define LOADXY(c, xc, yc)                                                   \
    float xc, yc;                                                           \
    {                                                                       \
        long s_ = base + (c)*16 + m16;                                      \
        long si_ = s_ < n ? s_ : (long)n - 1;                               \
        const float2 qv_ = ((const float2*)q)[si_];                         \
        xc = qv_.x; yc = qv_.y;                                             \
    }

#define ENC(c, xc, yc)                                                      \
    float t0_##c, t1_##c, E00_##c, E01_##c, E10_##c, E11_##c;               \
    mlp16(eWa, eWb, eBb, eB2, A2e, A3e, C3e, Z, xc, yc,                     \
          t0_##c, t1_##c, E00_##c, E01_##c, E10_##c, E11_##c);

#define DEC_STORE(c, xc, yc)                                                \
    {                                                                       \
        float q0_, q1_, D00_, D01_, D10_, D11_;                             \
        mlp16(dWa, dWb, dBb, dB2, A2d, A3d, C3d, Z, t0_##c, t1_##c,         \
              q0_, q1_, D00_, D01_, D10_, D11_);                            \
        long sp_ = base + (c)*16 + m16;                                     \
        if (g == (c) && sp_ < n) {                                          \
            float r2_ = fmaf(xc, xc, yc * yc);                              \
            float iv_ = __builtin_amdgcn_rcpf(r2_);                         \
            float rv_ = __builtin_amdgcn_rsqf(r2_ + 1e-8f);                 \
            ((float2*)(out))[sp_]          = make_float2(t0_##c, t1_##c);   \
            ((float4*)(out + 2*nn))[sp_]   = make_float4(E00_##c, E01_##c,  \
                                                         E10_##c, E11_##c); \
            ((float2*)(out + 6*nn))[sp_]   = make_float2(q0_, q1_);         \
            ((float4*)(out + 8*nn))[sp_]   = make_float4(D00_, D01_,        \
                                                         D10_, D11_);       \
            ((float4*)(out + 12*nn))[sp_]  = make_float4(-yc * iv_, xc * iv_,\
                                                         xc * rv_, yc * rv_);\
        }                                                                   \
    }

    LOADXY(0, x0, y0) LOADXY(1, x1, y1) LOADXY(2, x2, y2) LOADXY(3, x3, y3)

    // two chains in flight: enc0,enc1 | dec0,enc2 | dec1,enc3 | dec2 | dec3
    ENC(0, x0, y0)
    ENC(1, x1, y1)
    DEC_STORE(0, x0, y0)
    ENC(2, x2, y2)
    DEC_STORE(1, x1, y1)
    ENC(3, x3, y3)
    DEC_STORE(2, x2, y2)
    DEC_STORE(3, x3, y3)

#undef LOADXY
#undef ENC
#undef DEC_STORE
}

extern "C" void kernel_launch(void* const* d_in, const int* in_sizes, int n_in,
                              void* d_out, int out_size, void* d_ws, size_t ws_size,
                              hipStream_t stream)
{
    const float* q   = (const float*)d_in[0];
    const float* ew1 = (const float*)d_in[1];
    const float* eb1 = (const float*)d_in[2];
    const float* ew2 = (const float*)d_in[3];
    const float* eb2 = (const float*)d_in[4];
    const float* ew3 = (const float*)d_in[5];
    const float* eb3 = (const float*)d_in[6];
    const float* dw1 = (const float*)d_in[7];
    const float* db1 = (const float*)d_in[8];
    const float* dw2 = (const float*)d_in[9];
    const float* db2 = (const float*)d_in[10];
    const float* dw3 = (const float*)d_in[11];
    const float* db3 = (const float*)d_in[12];

    const int n = in_sizes[0] / 2;
    float* ws = (float*)d_ws;

    prep_kernel<<<1, 64, 0, stream>>>(ew1, eb1, ew2, eb2, ew3,
                                      dw1, db1, dw2, db2, dw3, ws);

    const int waves  = (n + 63) / 64;
    const int blocks = (waves + 3) / 4;
    ae_mfma_kernel<<<blocks, 256, 0, stream>>>(q, eb3, db3, ws, (float*)d_out, n);
}

// Round 4
// 121.861 us; speedup vs baseline: 1.3774x; 1.0449x over previous
//
#include <hip/hip_runtime.h>
#include <math.h>

// MFMA-based fused autoencoder fwd + Jacobians, 16x16x16, slice-unrolled.
// Per wave: 64 samples = 4 slices of 16 columns. Per layer:
//   D[i,s] = sum_j W[i,j] * H[j,s]  via  v_mfma_f32_16x16x16_bf16 (K=16 exact)
// Layouts: A: row=l&15, k=(l>>4)*4+j   B: k=(l>>4)*4+j, col=l&15
//          D: row=(l>>4)*4+reg, col=l&15
// D rows per lane == next-B k-range per lane -> layer2->3 lane-local; W3
// duplicated at rows {r: r&3<2} -> every lane's D regs 0,1 = outputs of its
// column -> enc->dec lane-local. No cross-lane ops anywhere.
//
// R4 (trans-pipe-dominant: ~60% of issue cycles are exp/log/rcp at 1/4 rate):
//  - log2-domain: W1,b1,b2 prescaled by log2e in prep; hidden acts carried as
//    h' = h*log2e; A3v = W3*ln2 restores natural units. Activ is now
//    t=exp2(-z') [neg modifier], w=1+t, sg=rcp(w), h'=z'+log2(w) -- no scale
//    mul, no final fma, log2 does not wait on rcp.
//  - L1 Jacobian weights folded into A-frags: ua = MFMA(A2a, Bsg) with
//    A2a = W2*diag(wa_nat), A2b = W2*diag(wb_nat); Bsg packed once, used
//    twice. Kills 8 muls + 1 pack4 per mlp16. A3j = W3 natural makes the
//    J-chain come out in natural units with zero runtime correction.
//  - __launch_bounds__(256,4): cap VGPR at 128 (occupancy cliff at >128).
// R3 lesson kept: no runtime-indexed private arrays (promote-alloca -> LDS).

typedef float  f32x4  __attribute__((ext_vector_type(4)));
typedef short  bf16x4 __attribute__((ext_vector_type(4)));

#define LOG2E 1.44269504089f
#define LN2   0.69314718056f

__device__ __forceinline__ unsigned short f2bf1(float f) {   // RNE (prep only)
    unsigned u = __builtin_bit_cast(unsigned, f);
    u += 0x7FFFu + ((u >> 16) & 1u);
    return (unsigned short)(u >> 16);
}

// packed truncating f32->bf16 pair: 1 x v_perm_b32 (a -> low half)
__device__ __forceinline__ unsigned packbf(float a, float b) {
    return __builtin_amdgcn_perm(__builtin_bit_cast(unsigned, b),
                                 __builtin_bit_cast(unsigned, a), 0x07060302u);
}

__device__ __forceinline__ bf16x4 pack4(float a, float b, float c, float d) {
    union { unsigned u[2]; bf16x4 f; } x;
    x.u[0] = packbf(a, b); x.u[1] = packbf(c, d);
    return x.f;
}

__device__ __forceinline__ f32x4 mfma16(bf16x4 a, bf16x4 b, f32x4 c) {
#if __has_builtin(__builtin_amdgcn_mfma_f32_16x16x16bf16_1k)
    return __builtin_amdgcn_mfma_f32_16x16x16bf16_1k(a, b, c, 0, 0, 0);
#else
    f32x4 d;
    asm("v_mfma_f32_16x16x16_bf16 %0, %1, %2, %3"
        : "=&v"(d) : "v"(a), "v"(b), "v"(c));
    return d;
#endif
}

__device__ __forceinline__ float exp2neg(float z) {          // exp2(-z), 1 inst
#if __has_builtin(__builtin_amdgcn_exp2f)
    return __builtin_amdgcn_exp2f(-z);
#else
    float r; asm("v_exp_f32 %0, -%1" : "=v"(r) : "v"(z)); return r;
#endif
}

// ---- ws layout (float offsets) ----
// encL1 [64][12] @0     (wa'|wb'|b1', all *LOG2E, rows g*4..g*4+3)
// decL1 @768
// encB2C [64][4] @1536  (b2[g*4+r]*LOG2E, C-init for zc')
// decB2C @1792
// frags (shorts) @2048: f*256 + t*4 + j for f =
//   0:A2e 1:A2ae 2:A2be 3:A3ve 4:A3je 5:A2d 6:A2ad 7:A2bd 8:A3vd 9:A3jd
__global__ void prep_kernel(
    const float* __restrict__ ew1, const float* __restrict__ eb1,
    const float* __restrict__ ew2, const float* __restrict__ eb2,
    const float* __restrict__ ew3,
    const float* __restrict__ dw1, const float* __restrict__ db1,
    const float* __restrict__ dw2, const float* __restrict__ db2,
    const float* __restrict__ dw3,
    float* __restrict__ ws)
{
    const int t = threadIdx.x;
    if (t >= 64) return;
    const int g = t >> 4, m = t & 15;
    unsigned short* frag = (unsigned short*)(ws + 2048);
#pragma unroll
    for (int j = 0; j < 4; ++j) {
        const int i = g * 4 + j;             // L1 neuron row == A-frag k index
        const float ewa = ew1[2*i], ewb = ew1[2*i+1];
        const float dwa = dw1[2*i], dwb = dw1[2*i+1];
        ws[t*12 + j]           = ewa * LOG2E;
        ws[t*12 + 4 + j]       = ewb * LOG2E;
        ws[t*12 + 8 + j]       = eb1[i] * LOG2E;
        ws[768 + t*12 + j]     = dwa * LOG2E;
        ws[768 + t*12 + 4 + j] = dwb * LOG2E;
        ws[768 + t*12 + 8 + j] = db1[i] * LOG2E;
        ws[1536 + t*4 + j]     = eb2[i] * LOG2E;
        ws[1792 + t*4 + j]     = db2[i] * LOG2E;
        const float e2 = ew2[m*16 + i], d2 = dw2[m*16 + i];
        frag[0*256 + t*4 + j] = f2bf1(e2);            // A2  (values, natural)
        frag[1*256 + t*4 + j] = f2bf1(e2 * ewa);      // A2a (J col a)
        frag[2*256 + t*4 + j] = f2bf1(e2 * ewb);      // A2b (J col b)
        frag[5*256 + t*4 + j] = f2bf1(d2);
        frag[6*256 + t*4 + j] = f2bf1(d2 * dwa);
        frag[7*256 + t*4 + j] = f2bf1(d2 * dwb);
        // A3: W3 duplicated at rows with (row&3)<2 -> every lane's D regs
        // 0,1 carry out0/out1 of its column.
        const int r3 = m & 3;
        const float e3 = (r3 < 2) ? ew3[r3*16 + i] : 0.0f;
        const float d3 = (r3 < 2) ? dw3[r3*16 + i] : 0.0f;
        frag[3*256 + t*4 + j] = f2bf1(e3 * LN2);      // A3v (values: B is h')
        frag[4*256 + t*4 + j] = f2bf1(e3);            // A3j (J: B is natural)
        frag[8*256 + t*4 + j] = f2bf1(d3 * LN2);
        frag[9*256 + t*4 + j] = f2bf1(d3);
    }
}

__device__ __forceinline__ void mlp16(
    f32x4 Wa, f32x4 Wb, f32x4 Bb, f32x4 B2c,
    bf16x4 A2, bf16x4 A2a, bf16x4 A2b, bf16x4 A3v, bf16x4 A3j,
    f32x4 C3, f32x4 Z,
    float x, float y,
    float& o0, float& o1, float& J00, float& J01, float& J10, float& J11)
{
    // L1: z' in log2 domain; h' = z' + log2(1+2^-z') = softplus(z)*log2e
    float h0, h1, h2v, h3, s0, s1, s2, s3;
    {
        float z, t, w;
        z = fmaf(Wa[0], x, fmaf(Wb[0], y, Bb[0]));
        t = exp2neg(z); w = 1.0f + t;
        s0 = __builtin_amdgcn_rcpf(w); h0 = z + __log2f(w);
        z = fmaf(Wa[1], x, fmaf(Wb[1], y, Bb[1]));
        t = exp2neg(z); w = 1.0f + t;
        s1 = __builtin_amdgcn_rcpf(w); h1 = z + __log2f(w);
        z = fmaf(Wa[2], x, fmaf(Wb[2], y, Bb[2]));
        t = exp2neg(z); w = 1.0f + t;
        s2 = __builtin_amdgcn_rcpf(w); h2v = z + __log2f(w);
        z = fmaf(Wa[3], x, fmaf(Wb[3], y, Bb[3]));
        t = exp2neg(z); w = 1.0f + t;
        s3 = __builtin_amdgcn_rcpf(w); h3 = z + __log2f(w);
    }
    const bf16x4 Bsg = pack4(s0, s1, s2, s3);        // packed once, used twice
    f32x4 zc = mfma16(A2,  pack4(h0, h1, h2v, h3), B2c);
    f32x4 ua = mfma16(A2a, Bsg, Z);
    f32x4 ub = mfma16(A2b, Bsg, Z);

    // L2: zc is already log2-domain (W2 natural x h' + b2*log2e)
    float g0, g1, g2, g3, sa0, sa1, sa2, sa3, sb0, sb1, sb2, sb3;
    {
        float t, w, r;
        t = exp2neg(zc[0]); w = 1.0f + t; r = __builtin_amdgcn_rcpf(w);
        g0 = zc[0] + __log2f(w); sa0 = r * ua[0]; sb0 = r * ub[0];
        t = exp2neg(zc[1]); w = 1.0f + t; r = __builtin_amdgcn_rcpf(w);
        g1 = zc[1] + __log2f(w); sa1 = r * ua[1]; sb1 = r * ub[1];
        t = exp2neg(zc[2]); w = 1.0f + t; r = __builtin_amdgcn_rcpf(w);
        g2 = zc[2] + __log2f(w); sa2 = r * ua[2]; sb2 = r * ub[2];
        t = exp2neg(zc[3]); w = 1.0f + t; r = __builtin_amdgcn_rcpf(w);
        g3 = zc[3] + __log2f(w); sa3 = r * ua[3]; sb3 = r * ub[3];
    }
    // D rows (g*4+r) == B k-range (g*4+j): feed straight back, lane-local.
    f32x4 oz = mfma16(A3v, pack4(g0,  g1,  g2,  g3),  C3);
    f32x4 oa = mfma16(A3j, pack4(sa0, sa1, sa2, sa3), Z);
    f32x4 ob = mfma16(A3j, pack4(sb0, sb1, sb2, sb3), Z);
    o0 = oz[0]; o1 = oz[1];
    J00 = oa[0]; J10 = oa[1]; J01 = ob[0]; J11 = ob[1];
}

__global__ __launch_bounds__(256, 4) void ae_mfma_kernel(
    const float* __restrict__ q,
    const float* __restrict__ eb3, const float* __restrict__ db3,
    const float* __restrict__ ws, float* __restrict__ out, int n)
{
    const int lane = threadIdx.x & 63;
    const int wv = blockIdx.x * 4 + (threadIdx.x >> 6);
    const int g = lane >> 4, m16 = lane & 15;
    const long base = (long)wv * 64;           // 64 samples per wave
    if (base >= n) return;                     // wave-uniform exit

    const f32x4 eWa = *(const f32x4*)(ws + (size_t)lane*12);
    const f32x4 eWb = *(const f32x4*)(ws + (size_t)lane*12 + 4);
    const f32x4 eBb = *(const f32x4*)(ws + (size_t)lane*12 + 8);
    const f32x4 dWa = *(const f32x4*)(ws + 768 + (size_t)lane*12);
    const f32x4 dWb = *(const f32x4*)(ws + 768 + (size_t)lane*12 + 4);
    const f32x4 dBb = *(const f32x4*)(ws + 768 + (size_t)lane*12 + 8);
    const f32x4 eB2 = *(const f32x4*)(ws + 1536 + (size_t)lane*4);
    const f32x4 dB2 = *(const f32x4*)(ws + 1792 + (size_t)lane*4);
    const bf16x4* fr = (const bf16x4*)(ws + 2048);
    const bf16x4 A2e  = fr[0*64 + lane], A2ae = fr[1*64 + lane];
    const bf16x4 A2be = fr[2*64 + lane];
    const bf16x4 A3ve = fr[3*64 + lane], A3je = fr[4*64 + lane];
    const bf16x4 A2d  = fr[5*64 + lane], A2ad = fr[6*64 + lane];
    const bf16x4 A2bd = fr[7*64 + lane];
    const bf16x4 A3vd = fr[8*64 + lane], A3jd = fr[9*64 + lane];
    f32x4 C3e; C3e[0] = eb3[0]; C3e[1] = eb3[1]; C3e[2] = 0.0f; C3e[3] = 0.0f;
    f32x4 C3d; C3d[0] = db3[0]; C3d[1] = db3[1]; C3d[2] = 0.0f; C3d[3] = 0.0f;
    f32x4 Z;   Z[0] = 0.0f; Z[1] = 0.0f; Z[2] = 0.0f; Z[3] = 0.0f;

    const size_t nn = (size_t)n;

#define LOADXY(c, xc, yc)                                                   \
    float xc, yc;                                                           \
    {                                                                       \
        long s_ = base + (c)*16 + m16;                                      \
        long si_ = s_ < n ? s_ : (long)n - 1;                               \
        const float2 qv_ = ((const float2*)q)[si_];                         \
        xc = qv_.x; yc = qv_.y;                                             \
    }

#define ENC(c, xc, yc)                                                      \
    float t0_##c, t1_##c, E00_##c, E01_##c, E10_##c, E11_##c;               \
    mlp16(eWa, eWb, eBb, eB2, A2e, A2ae, A2be, A3ve, A3je, C3e, Z, xc, yc,  \
          t0_##c, t1_##c, E00_##c, E01_##c, E10_##c, E11_##c);

#define DEC_STORE(c, xc, yc)                                                \
    {                                                                       \
        float q0_, q1_, D00_, D01_, D10_, D11_;                             \
        mlp16(dWa, dWb, dBb, dB2, A2d, A2ad, A2bd, A3vd, A3jd, C3d, Z,      \
              t0_##c, t1_##c, q0_, q1_, D00_, D01_, D10_, D11_);            \
        long sp_ = base + (c)*16 + m16;                                     \
        if (g == (c) && sp_ < n) {                                          \
            float r2_ = fmaf(xc, xc, yc * yc);                              \
            float iv_ = __builtin_amdgcn_rcpf(r2_);                         \
            float rv_ = __builtin_amdgcn_rsqf(r2_ + 1e-8f);                 \
            ((float2*)(out))[sp_]          = make_float2(t0_##c, t1_##c);   \
            ((float4*)(out + 2*nn))[sp_]   = make_float4(E00_##c, E01_##c,  \
                                                         E10_##c, E11_##c); \
            ((float2*)(out + 6*nn))[sp_]   = make_float2(q0_, q1_);         \
            ((float4*)(out + 8*nn))[sp_]   = make_float4(D00_, D01_,        \
                                                         D10_, D11_);       \
            ((float4*)(out + 12*nn))[sp_]  = make_float4(-yc * iv_, xc * iv_,\
                                                         xc * rv_, yc * rv_);\
        }                                                                   \
    }

    LOADXY(0, x0, y0) LOADXY(1, x1, y1) LOADXY(2, x2, y2) LOADXY(3, x3, y3)

    // two chains in flight: enc0,enc1 | dec0,enc2 | dec1,enc3 | dec2 | dec3
    ENC(0, x0, y0)
    ENC(1, x1, y1)
    DEC_STORE(0, x0, y0)
    ENC(2, x2, y2)
    DEC_STORE(1, x1, y1)
    ENC(3, x3, y3)
    DEC_STORE(2, x2, y2)
    DEC_STORE(3, x3, y3)

#undef LOADXY
#undef ENC
#undef DEC_STORE
}

extern "C" void kernel_launch(void* const* d_in, const int* in_sizes, int n_in,
                              void* d_out, int out_size, void* d_ws, size_t ws_size,
                              hipStream_t stream)
{
    const float* q   = (const float*)d_in[0];
    const float* ew1 = (const float*)d_in[1];
    const float* eb1 = (const float*)d_in[2];
    const float* ew2 = (const float*)d_in[3];
    const float* eb2 = (const float*)d_in[4];
    const float* ew3 = (const float*)d_in[5];
    const float* eb3 = (const float*)d_in[6];
    const float* dw1 = (const float*)d_in[7];
    const float* db1 = (const float*)d_in[8];
    const float* dw2 = (const float*)d_in[9];
    const float* db2 = (const float*)d_in[10];
    const float* dw3 = (const float*)d_in[11];
    const float* db3 = (const float*)d_in[12];

    const int n = in_sizes[0] / 2;
    float* ws = (float*)d_ws;

    prep_kernel<<<1, 64, 0, stream>>>(ew1, eb1, ew2, eb2, ew3,
                                      dw1, db1, dw2, db2, dw3, ws);

    const int waves  = (n + 63) / 64;
    const int blocks = (waves + 3) / 4;
    ae_mfma_kernel<<<blocks, 256, 0, stream>>>(q, eb3, db3, ws, (float*)d_out, n);
}

// Round 5
// 120.256 us; speedup vs baseline: 1.3957x; 1.0133x over previous
//
#include <hip/hip_runtime.h>
#include <math.h>

// MFMA-based fused autoencoder fwd + Jacobians, 16x16x16, slice-unrolled.
// Per wave: 64 samples = 4 slices of 16 columns. Per layer:
//   D[i,s] = sum_j W[i,j] * H[j,s]  via  v_mfma_f32_16x16x16_bf16 (K=16 exact)
// Layouts: A: row=l&15, k=(l>>4)*4+j   B: k=(l>>4)*4+j, col=l&15
//          D: row=(l>>4)*4+reg, col=l&15
// D rows per lane == next-B k-range per lane -> layer2->3 lane-local; W3
// duplicated at rows {r: r&3<2} -> every lane's D regs 0,1 = outputs of its
// column -> enc->dec lane-local. No cross-lane ops anywhere.
//
// R5 (latency-bound: occupancy ~1.5 waves/SIMD, VALUBusy ~50%, issue floor
// ~14us vs ~38us measured):
//  - 4-deep chains: ENC0..3 then DEC0..3 (was 2-deep). 4 independent
//    trans+MFMA chains per wave hide each other's latency.
//  - x,y no longer held live for the analytic-J epilogue: q reloaded at
//    store time (L2-hit, off critical path) -> ~8 VGPR freed to pay for
//    the deeper pipeline. __launch_bounds__(256,4) caps at 128 VGPR.
// R4 kept: log2-domain activations (3 trans/activ, provably minimal),
//   L1-Jacobian folded into A-frags (A2a/A2b), shared C tuples.
// R3 lesson kept: no runtime-indexed private arrays (promote-alloca -> LDS).

typedef float  f32x4  __attribute__((ext_vector_type(4)));
typedef short  bf16x4 __attribute__((ext_vector_type(4)));

#define LOG2E 1.44269504089f
#define LN2   0.69314718056f

__device__ __forceinline__ unsigned short f2bf1(float f) {   // RNE (prep only)
    unsigned u = __builtin_bit_cast(unsigned, f);
    u += 0x7FFFu + ((u >> 16) & 1u);
    return (unsigned short)(u >> 16);
}

// packed truncating f32->bf16 pair: 1 x v_perm_b32 (a -> low half)
__device__ __forceinline__ unsigned packbf(float a, float b) {
    return __builtin_amdgcn_perm(__builtin_bit_cast(unsigned, b),
                                 __builtin_bit_cast(unsigned, a), 0x07060302u);
}

__device__ __forceinline__ bf16x4 pack4(float a, float b, float c, float d) {
    union { unsigned u[2]; bf16x4 f; } x;
    x.u[0] = packbf(a, b); x.u[1] = packbf(c, d);
    return x.f;
}

__device__ __forceinline__ f32x4 mfma16(bf16x4 a, bf16x4 b, f32x4 c) {
#if __has_builtin(__builtin_amdgcn_mfma_f32_16x16x16bf16_1k)
    return __builtin_amdgcn_mfma_f32_16x16x16bf16_1k(a, b, c, 0, 0, 0);
#else
    f32x4 d;
    asm("v_mfma_f32_16x16x16_bf16 %0, %1, %2, %3"
        : "=&v"(d) : "v"(a), "v"(b), "v"(c));
    return d;
#endif
}

__device__ __forceinline__ float exp2neg(float z) {          // exp2(-z), 1 inst
#if __has_builtin(__builtin_amdgcn_exp2f)
    return __builtin_amdgcn_exp2f(-z);
#else
    float r; asm("v_exp_f32 %0, -%1" : "=v"(r) : "v"(z)); return r;
#endif
}

// ---- ws layout (float offsets) ----
// encL1 [64][12] @0     (wa'|wb'|b1', all *LOG2E, rows g*4..g*4+3)
// decL1 @768
// encB2C [64][4] @1536  (b2[g*4+r]*LOG2E, C-init for zc')
// decB2C @1792
// frags (shorts) @2048: f*256 + t*4 + j for f =
//   0:A2e 1:A2ae 2:A2be 3:A3ve 4:A3je 5:A2d 6:A2ad 7:A2bd 8:A3vd 9:A3jd
__global__ void prep_kernel(
    const float* __restrict__ ew1, const float* __restrict__ eb1,
    const float* __restrict__ ew2, const float* __restrict__ eb2,
    const float* __restrict__ ew3,
    const float* __restrict__ dw1, const float* __restrict__ db1,
    const float* __restrict__ dw2, const float* __restrict__ db2,
    const float* __restrict__ dw3,
    float* __restrict__ ws)
{
    const int t = threadIdx.x;
    if (t >= 64) return;
    const int g = t >> 4, m = t & 15;
    unsigned short* frag = (unsigned short*)(ws + 2048);
#pragma unroll
    for (int j = 0; j < 4; ++j) {
        const int i = g * 4 + j;             // L1 neuron row == A-frag k index
        const float ewa = ew1[2*i], ewb = ew1[2*i+1];
        const float dwa = dw1[2*i], dwb = dw1[2*i+1];
        ws[t*12 + j]           = ewa * LOG2E;
        ws[t*12 + 4 + j]       = ewb * LOG2E;
        ws[t*12 + 8 + j]       = eb1[i] * LOG2E;
        ws[768 + t*12 + j]     = dwa * LOG2E;
        ws[768 + t*12 + 4 + j] = dwb * LOG2E;
        ws[768 + t*12 + 8 + j] = db1[i] * LOG2E;
        ws[1536 + t*4 + j]     = eb2[i] * LOG2E;
        ws[1792 + t*4 + j]     = db2[i] * LOG2E;
        const float e2 = ew2[m*16 + i], d2 = dw2[m*16 + i];
        frag[0*256 + t*4 + j] = f2bf1(e2);            // A2  (values, natural)
        frag[1*256 + t*4 + j] = f2bf1(e2 * ewa);      // A2a (J col a)
        frag[2*256 + t*4 + j] = f2bf1(e2 * ewb);      // A2b (J col b)
        frag[5*256 + t*4 + j] = f2bf1(d2);
        frag[6*256 + t*4 + j] = f2bf1(d2 * dwa);
        frag[7*256 + t*4 + j] = f2bf1(d2 * dwb);
        // A3: W3 duplicated at rows with (row&3)<2 -> every lane's D regs
        // 0,1 carry out0/out1 of its column.
        const int r3 = m & 3;
        const float e3 = (r3 < 2) ? ew3[r3*16 + i] : 0.0f;
        const float d3 = (r3 < 2) ? dw3[r3*16 + i] : 0.0f;
        frag[3*256 + t*4 + j] = f2bf1(e3 * LN2);      // A3v (values: B is h')
        frag[4*256 + t*4 + j] = f2bf1(e3);            // A3j (J: B is natural)
        frag[8*256 + t*4 + j] = f2bf1(d3 * LN2);
        frag[9*256 + t*4 + j] = f2bf1(d3);
    }
}

__device__ __forceinline__ void mlp16(
    f32x4 Wa, f32x4 Wb, f32x4 Bb, f32x4 B2c,
    bf16x4 A2, bf16x4 A2a, bf16x4 A2b, bf16x4 A3v, bf16x4 A3j,
    f32x4 C3, f32x4 Z,
    float x, float y,
    float& o0, float& o1, float& J00, float& J01, float& J10, float& J11)
{
    // L1: z' in log2 domain; h' = z' + log2(1+2^-z') = softplus(z)*log2e
    float h0, h1, h2v, h3, s0, s1, s2, s3;
    {
        float z, t, w;
        z = fmaf(Wa[0], x, fmaf(Wb[0], y, Bb[0]));
        t = exp2neg(z); w = 1.0f + t;
        s0 = __builtin_amdgcn_rcpf(w); h0 = z + __log2f(w);
        z = fmaf(Wa[1], x, fmaf(Wb[1], y, Bb[1]));
        t = exp2neg(z); w = 1.0f + t;
        s1 = __builtin_amdgcn_rcpf(w); h1 = z + __log2f(w);
        z = fmaf(Wa[2], x, fmaf(Wb[2], y, Bb[2]));
        t = exp2neg(z); w = 1.0f + t;
        s2 = __builtin_amdgcn_rcpf(w); h2v = z + __log2f(w);
        z = fmaf(Wa[3], x, fmaf(Wb[3], y, Bb[3]));
        t = exp2neg(z); w = 1.0f + t;
        s3 = __builtin_amdgcn_rcpf(w); h3 = z + __log2f(w);
    }
    const bf16x4 Bsg = pack4(s0, s1, s2, s3);        // packed once, used twice
    f32x4 zc = mfma16(A2,  pack4(h0, h1, h2v, h3), B2c);
    f32x4 ua = mfma16(A2a, Bsg, Z);
    f32x4 ub = mfma16(A2b, Bsg, Z);

    // L2: zc is already log2-domain (W2 natural x h' + b2*log2e)
    float g0, g1, g2, g3, sa0, sa1, sa2, sa3, sb0, sb1, sb2, sb3;
    {
        float t, w, r;
        t = exp2neg(zc[0]); w = 1.0f + t; r = __builtin_amdgcn_rcpf(w);
        g0 = zc[0] + __log2f(w); sa0 = r * ua[0]; sb0 = r * ub[0];
        t = exp2neg(zc[1]); w = 1.0f + t; r = __builtin_amdgcn_rcpf(w);
        g1 = zc[1] + __log2f(w); sa1 = r * ua[1]; sb1 = r * ub[1];
        t = exp2neg(zc[2]); w = 1.0f + t; r = __builtin_amdgcn_rcpf(w);
        g2 = zc[2] + __log2f(w); sa2 = r * ua[2]; sb2 = r * ub[2];
        t = exp2neg(zc[3]); w = 1.0f + t; r = __builtin_amdgcn_rcpf(w);
        g3 = zc[3] + __log2f(w); sa3 = r * ua[3]; sb3 = r * ub[3];
    }
    // D rows (g*4+r) == B k-range (g*4+j): feed straight back, lane-local.
    f32x4 oz = mfma16(A3v, pack4(g0,  g1,  g2,  g3),  C3);
    f32x4 oa = mfma16(A3j, pack4(sa0, sa1, sa2, sa3), Z);
    f32x4 ob = mfma16(A3j, pack4(sb0, sb1, sb2, sb3), Z);
    o0 = oz[0]; o1 = oz[1];
    J00 = oa[0]; J10 = oa[1]; J01 = ob[0]; J11 = ob[1];
}

__global__ __launch_bounds__(256, 4) void ae_mfma_kernel(
    const float* __restrict__ q,
    const float* __restrict__ eb3, const float* __restrict__ db3,
    const float* __restrict__ ws, float* __restrict__ out, int n)
{
    const int lane = threadIdx.x & 63;
    const int wv = blockIdx.x * 4 + (threadIdx.x >> 6);
    const int g = lane >> 4, m16 = lane & 15;
    const long base = (long)wv * 64;           // 64 samples per wave
    if (base >= n) return;                     // wave-uniform exit

    const f32x4 eWa = *(const f32x4*)(ws + (size_t)lane*12);
    const f32x4 eWb = *(const f32x4*)(ws + (size_t)lane*12 + 4);
    const f32x4 eBb = *(const f32x4*)(ws + (size_t)lane*12 + 8);
    const f32x4 dWa = *(const f32x4*)(ws + 768 + (size_t)lane*12);
    const f32x4 dWb = *(const f32x4*)(ws + 768 + (size_t)lane*12 + 4);
    const f32x4 dBb = *(const f32x4*)(ws + 768 + (size_t)lane*12 + 8);
    const f32x4 eB2 = *(const f32x4*)(ws + 1536 + (size_t)lane*4);
    const f32x4 dB2 = *(const f32x4*)(ws + 1792 + (size_t)lane*4);
    const bf16x4* fr = (const bf16x4*)(ws + 2048);
    const bf16x4 A2e  = fr[0*64 + lane], A2ae = fr[1*64 + lane];
    const bf16x4 A2be = fr[2*64 + lane];
    const bf16x4 A3ve = fr[3*64 + lane], A3je = fr[4*64 + lane];
    const bf16x4 A2d  = fr[5*64 + lane], A2ad = fr[6*64 + lane];
    const bf16x4 A2bd = fr[7*64 + lane];
    const bf16x4 A3vd = fr[8*64 + lane], A3jd = fr[9*64 + lane];
    f32x4 C3e; C3e[0] = eb3[0]; C3e[1] = eb3[1]; C3e[2] = 0.0f; C3e[3] = 0.0f;
    f32x4 C3d; C3d[0] = db3[0]; C3d[1] = db3[1]; C3d[2] = 0.0f; C3d[3] = 0.0f;
    f32x4 Z;   Z[0] = 0.0f; Z[1] = 0.0f; Z[2] = 0.0f; Z[3] = 0.0f;

    const size_t nn = (size_t)n;

#define LOADXY(c, xc, yc)                                                   \
    float xc, yc;                                                           \
    {                                                                       \
        long s_ = base + (c)*16 + m16;                                      \
        long si_ = s_ < n ? s_ : (long)n - 1;                               \
        const float2 qv_ = ((const float2*)q)[si_];                         \
        xc = qv_.x; yc = qv_.y;                                             \
    }

#define ENC(c, xc, yc)                                                      \
    float t0_##c, t1_##c, E00_##c, E01_##c, E10_##c, E11_##c;               \
    mlp16(eWa, eWb, eBb, eB2, A2e, A2ae, A2be, A3ve, A3je, C3e, Z, xc, yc,  \
          t0_##c, t1_##c, E00_##c, E01_##c, E10_##c, E11_##c);

// q reloaded at store time (L2-hit) so x,y need not stay live through the
// 4-deep pipeline -- frees ~8 VGPR for the extra chains.
#define DEC_STORE(c)                                                        \
    {                                                                       \
        float q0_, q1_, D00_, D01_, D10_, D11_;                             \
        mlp16(dWa, dWb, dBb, dB2, A2d, A2ad, A2bd, A3vd, A3jd, C3d, Z,      \
              t0_##c, t1_##c, q0_, q1_, D00_, D01_, D10_, D11_);            \
        long sp_ = base + (c)*16 + m16;                                     \
        if (g == (c) && sp_ < n) {                                          \
            const float2 qv_ = ((const float2*)q)[sp_];                     \
            const float xc = qv_.x, yc = qv_.y;                             \
            float r2_ = fmaf(xc, xc, yc * yc);                              \
            float iv_ = __builtin_amdgcn_rcpf(r2_);                         \
            float rv_ = __builtin_amdgcn_rsqf(r2_ + 1e-8f);                 \
            ((float2*)(out))[sp_]          = make_float2(t0_##c, t1_##c);   \
            ((float4*)(out + 2*nn))[sp_]   = make_float4(E00_##c, E01_##c,  \
                                                         E10_##c, E11_##c); \
            ((float2*)(out + 6*nn))[sp_]   = make_float2(q0_, q1_);         \
            ((float4*)(out + 8*nn))[sp_]   = make_float4(D00_, D01_,        \
                                                         D10_, D11_);       \
            ((float4*)(out + 12*nn))[sp_]  = make_float4(-yc * iv_, xc * iv_,\
                                                         xc * rv_, yc * rv_);\
        }                                                                   \
    }

    LOADXY(0, x0, y0) LOADXY(1, x1, y1) LOADXY(2, x2, y2) LOADXY(3, x3, y3)

    // 4 independent chains in flight: all encoders, then all decoders
    ENC(0, x0, y0)
    ENC(1, x1, y1)
    ENC(2, x2, y2)
    ENC(3, x3, y3)
    DEC_STORE(0)
    DEC_STORE(1)
    DEC_STORE(2)
    DEC_STORE(3)

#undef LOADXY
#undef ENC
#undef DEC_STORE
}

extern "C" void kernel_launch(void* const* d_in, const int* in_sizes, int n_in,
                              void* d_out, int out_size, void* d_ws, size_t ws_size,
                              hipStream_t stream)
{
    const float* q   = (const float*)d_in[0];
    const float* ew1 = (const float*)d_in[1];
    const float* eb1 = (const float*)d_in[2];
    const float* ew2 = (const float*)d_in[3];
    const float* eb2 = (const float*)d_in[4];
    const float* ew3 = (const float*)d_in[5];
    const float* eb3 = (const float*)d_in[6];
    const float* dw1 = (const float*)d_in[7];
    const float* db1 = (const float*)d_in[8];
    const float* dw2 = (const float*)d_in[9];
    const float* db2 = (const float*)d_in[10];
    const float* dw3 = (const float*)d_in[11];
    const float* db3 = (const float*)d_in[12];

    const int n = in_sizes[0] / 2;
    float* ws = (float*)d_ws;

    prep_kernel<<<1, 64, 0, stream>>>(ew1, eb1, ew2, eb2, ew3,
                                      dw1, db1, dw2, db2, dw3, ws);

    const int waves  = (n + 63) / 64;
    const int blocks = (waves + 3) / 4;
    ae_mfma_kernel<<<blocks, 256, 0, stream>>>(q, eb3, db3, ws, (float*)d_out, n);
}